// Round 7
// baseline (9215.726 us; speedup 1.0000x reference)
//
#include <hip/hip_runtime.h>

// ============================================================================
// LITERAL reference implementation, per-graph fused. No algebraic shortcuts:
//   h = X W; al_s = h.a_src; al_d = h.a_dst; per-edge leaky logits over the
//   real edge list (+self-loops); segment max/sum softmax; edge messages;
//   +bias (+relu); last layer: conn = h h^T, z = conn ws + bs, sigmoid.
// ============================================================================

template<int LAST, int KDIM, int NDIM>
__global__ __launch_bounds__(256) void gat_literal(
    const float* __restrict__ Xin, long ldin,
    const float* __restrict__ W,      // [KDIM][NDIM] row-major
    const float* __restrict__ avs,    // [NDIM]
    const float* __restrict__ avd,    // [NDIM]
    const float* __restrict__ bias,   // [NDIM]
    const int*   __restrict__ ei, int E,
    float* __restrict__ Xout,         // [M][512] (layers 1-3)
    const float* __restrict__ wsc, const float* __restrict__ bsp,
    float* __restrict__ outp)         // [B*19] (last layer)
{
    __shared__ float Xs[19 * 512];          // input rows, then reused for out rows
    __shared__ float Hs[19 * 512];          // h = X W
    __shared__ float as_[512], ad_[512], bi_[512];
    __shared__ short srcL[384], dstL[384];
    __shared__ float alphaE[384];
    __shared__ short eidx[384];             // CSR edge ids by dst
    __shared__ int   off[20];
    __shared__ int   cnt[19];
    __shared__ float alS[19], alD[19], mxs[19], sms[19];
    __shared__ float connL[361];
    __shared__ float wl[19];

    const int tid = threadIdx.x;
    const int g = blockIdx.x;
    const int Etot = E + 19;

    // ---- load input rows, vectors, edge list (+self-loops) ----
    for (int idx = tid; idx < 19 * KDIM; idx += 256) {
        int n = idx / KDIM, k = idx % KDIM;
        Xs[n * 512 + k] = Xin[(size_t)(g * 19 + n) * ldin + k];
    }
    for (int c = tid; c < NDIM; c += 256) { as_[c] = avs[c]; ad_[c] = avd[c]; bi_[c] = bias[c]; }
    for (int e = tid; e < E; e += 256) { srcL[e] = (short)ei[e]; dstL[e] = (short)ei[E + e]; }
    if (tid < 19) { srcL[E + tid] = (short)tid; dstL[E + tid] = (short)tid; }
    if (LAST && tid < 19) wl[tid] = wsc[tid];
    if (tid < 19) cnt[tid] = 0;
    __syncthreads();

    // ---- h = Xs @ W : thread owns column c for all 19 rows ----
    for (int it = 0; it < NDIM / 256; ++it) {
        int c = tid + it * 256;
        float acc[19];
#pragma unroll
        for (int n = 0; n < 19; ++n) acc[n] = 0.f;
        for (int k = 0; k < KDIM; ++k) {
            float w = W[(size_t)k * NDIM + c];
#pragma unroll
            for (int n = 0; n < 19; ++n) acc[n] += Xs[n * 512 + k] * w;
        }
#pragma unroll
        for (int n = 0; n < 19; ++n) Hs[n * 512 + c] = acc[n];
    }
    __syncthreads();

    // ---- logits al_s = h.a_src, al_d = h.a_dst ----
    if (tid < 19) {
        float a = 0.f;
        const float* hr = &Hs[tid * 512];
        for (int c = 0; c < NDIM; ++c) a += hr[c] * as_[c];
        alS[tid] = a;
    } else if (tid >= 64 && tid < 83) {
        int n = tid - 64;
        float a = 0.f;
        const float* hr = &Hs[n * 512];
        for (int c = 0; c < NDIM; ++c) a += hr[c] * ad_[c];
        alD[n] = a;
    }
    __syncthreads();

    // ---- CSR bucket edges by dst ----
    for (int e = tid; e < Etot; e += 256) atomicAdd(&cnt[dstL[e]], 1);
    __syncthreads();
    if (tid == 0) {
        off[0] = 0;
        for (int n = 0; n < 19; ++n) off[n + 1] = off[n] + cnt[n];
    }
    __syncthreads();
    if (tid < 19) cnt[tid] = 0;
    __syncthreads();
    for (int e = tid; e < Etot; e += 256) {
        int d = dstL[e];
        int p = off[d] + atomicAdd(&cnt[d], 1);
        eidx[p] = (short)e;
    }
    __syncthreads();

    // ---- segment max / sum over incoming edges (literal, duplicates natural) ----
    if (tid < 19) {
        float m = -1e30f;
        float ad = alD[tid];
        for (int j = off[tid]; j < off[tid + 1]; ++j) {
            int e = eidx[j];
            float le = alS[srcL[e]] + ad;
            le = le > 0.f ? le : 0.2f * le;
            m = fmaxf(m, le);
        }
        float s = 0.f;
        for (int j = off[tid]; j < off[tid + 1]; ++j) {
            int e = eidx[j];
            float le = alS[srcL[e]] + ad;
            le = le > 0.f ? le : 0.2f * le;
            s += __expf(le - m);
        }
        mxs[tid] = m; sms[tid] = s;
    }
    __syncthreads();
    for (int e = tid; e < Etot; e += 256) {
        int d = dstL[e];
        float le = alS[srcL[e]] + alD[d];
        le = le > 0.f ? le : 0.2f * le;
        alphaE[e] = __expf(le - mxs[d]) / sms[d];
    }
    __syncthreads();

    // ---- messages: out[n][c] = sum_{e:dst=n} alpha_e * h[src_e][c] (+bias, relu) ----
    for (int idx = tid; idx < 19 * NDIM; idx += 256) {
        int n = idx / NDIM, c = idx % NDIM;
        float acc = 0.f;
        for (int j = off[n]; j < off[n + 1]; ++j) {
            int e = eidx[j];
            acc += alphaE[e] * Hs[srcL[e] * 512 + c];
        }
        float v = acc + bi_[c];
        if (!LAST) v = fmaxf(v, 0.f);
        Xs[n * 512 + c] = v;     // reuse Xs as the out-row buffer
    }
    __syncthreads();

    if (!LAST) {
        for (int idx = tid; idx < 19 * NDIM; idx += 256) {
            int n = idx / NDIM, c = idx % NDIM;
            Xout[(size_t)(g * 19 + n) * 512 + c] = Xs[n * 512 + c];
        }
    } else {
        // ---- literal scoring: conn = h h^T ; z = conn @ ws + bs ; sigmoid ----
        for (int idx = tid; idx < 361; idx += 256) {
            int n = idx / 19, m = idx % 19;
            float a = 0.f;
            for (int c = 0; c < NDIM; ++c) a += Xs[n * 512 + c] * Xs[m * 512 + c];
            connL[idx] = a;
        }
        __syncthreads();
        if (tid < 19) {
            float z = 0.f;
#pragma unroll
            for (int m = 0; m < 19; ++m) z += connL[tid * 19 + m] * wl[m];
            outp[(size_t)g * 19 + tid] = 1.f / (1.f + __expf(-(z + bsp[0])));
        }
    }
}

// ---------- launch ----------
extern "C" void kernel_launch(void* const* d_in, const int* in_sizes, int n_in,
                              void* d_out, int out_size, void* d_ws, size_t ws_size,
                              hipStream_t stream) {
    const float* x   = (const float*)d_in[0];
    const int*   ei  = (const int*)d_in[1];
    const float* W[4]  = {(const float*)d_in[3], (const float*)d_in[7], (const float*)d_in[11], (const float*)d_in[15]};
    const float* As[4] = {(const float*)d_in[4], (const float*)d_in[8], (const float*)d_in[12], (const float*)d_in[16]};
    const float* Ad[4] = {(const float*)d_in[5], (const float*)d_in[9], (const float*)d_in[13], (const float*)d_in[17]};
    const float* Bi[4] = {(const float*)d_in[6], (const float*)d_in[10], (const float*)d_in[14], (const float*)d_in[18]};
    const float* wsc = (const float*)d_in[19];
    const float* bsp = (const float*)d_in[20];
    float* out = (float*)d_out;

    const int Bq = in_sizes[0] / (19 * 256);   // 4096
    const int E  = in_sizes[1] / 2;            // 342

    float* X = (float*)d_ws;                   // [M][512] f32, 159.4 MB

    gat_literal<0, 256, 512><<<Bq, 256, 0, stream>>>(x, 256, W[0], As[0], Ad[0], Bi[0],
                                                     ei, E, X, nullptr, nullptr, nullptr);
    gat_literal<0, 512, 512><<<Bq, 256, 0, stream>>>(X, 512, W[1], As[1], Ad[1], Bi[1],
                                                     ei, E, X, nullptr, nullptr, nullptr);
    gat_literal<0, 512, 512><<<Bq, 256, 0, stream>>>(X, 512, W[2], As[2], Ad[2], Bi[2],
                                                     ei, E, X, nullptr, nullptr, nullptr);
    gat_literal<1, 512, 256><<<Bq, 256, 0, stream>>>(X, 512, W[3], As[3], Ad[3], Bi[3],
                                                     ei, E, nullptr, wsc, bsp, out);
}

// Round 8
// 2780.275 us; speedup vs baseline: 3.3147x; 3.3147x over previous
//
#include <hip/hip_runtime.h>

typedef short bf16x8 __attribute__((ext_vector_type(8)));
typedef float f32x4 __attribute__((ext_vector_type(4)));

// ---------- helpers ----------
__device__ __forceinline__ unsigned short f2b(float f) {
    unsigned int u = __float_as_uint(f);
    unsigned int r = (u + 0x7FFFu + ((u >> 16) & 1u)) >> 16;   // RNE
    return (unsigned short)r;
}
__device__ __forceinline__ float b2f(unsigned short u) {
    return __uint_as_float(((unsigned int)u) << 16);
}
__device__ __forceinline__ void gl_lds16(const void* g, void* l) {
    __builtin_amdgcn_global_load_lds(
        (const __attribute__((address_space(1))) unsigned int*)g,
        (__attribute__((address_space(3))) unsigned int*)l, 16, 0, 0);
}

// X layout: [M][1024] shorts; hi at cols [0,512), lo at [512,1024); first C valid.

// ---------- prep: x f32 -> X hi/lo (C=256) ----------
__global__ __launch_bounds__(256) void xcvt_k(const float* __restrict__ x,
                                              unsigned short* __restrict__ X, long nq) {
    long i = blockIdx.x * 256L + threadIdx.x;
    long st = gridDim.x * 256L;
    for (; i < nq; i += st) {
        long r = i >> 6; int q = (int)(i & 63);
        float4 v = *(const float4*)(x + r * 256 + q * 4);
        ushort4 h, l;
        h.x = f2b(v.x); l.x = f2b(v.x - b2f(h.x));
        h.y = f2b(v.y); l.y = f2b(v.y - b2f(h.y));
        h.z = f2b(v.z); l.z = f2b(v.z - b2f(h.z));
        h.w = f2b(v.w); l.w = f2b(v.w - b2f(h.w));
        *(ushort4*)(X + r * 1024 + q * 4) = h;
        *(ushort4*)(X + r * 1024 + 512 + q * 4) = l;
    }
}

// ---------- prep: W [K][N] f32 -> W2 [N][2K] = [hi | lo] ----------
__global__ __launch_bounds__(256) void wtrans_k(const float* __restrict__ W,
                                                unsigned short* __restrict__ W2, int K, int N) {
    int idx = blockIdx.x * blockDim.x + threadIdx.x;
    if (idx >= K * N) return;
    int n = idx / K, k = idx % K;
    float w = W[(size_t)k * N + n];
    unsigned short hi = f2b(w);
    size_t b = (size_t)n * 2 * K;
    W2[b + k] = hi;
    W2[b + K + k] = f2b(w - b2f(hi));
}

// ---------- in-place hi/lo MFMA GEMM: X <- X @ W  (no bias / no act) ----------
// Contraction over 3K: seg0 Ahi*Whi, seg1 Ahi*Wlo, seg2 Alo*Whi.
// Block owns 128 rows x ALL N cols -> writes only rows it reads -> in-place safe.
template<int NI>   // N = NI*64 (8 -> 512, 4 -> 256)
__global__ __launch_bounds__(512, 2) void gemm_inplace(unsigned short* __restrict__ X,
                                                       const unsigned short* __restrict__ W2,
                                                       int K) {
    constexpr int BN = NI * 64;
    __shared__ unsigned short As[128 * 64];
    __shared__ unsigned short Bs[BN * 64];
    const int tid = threadIdx.x;
    const int lane = tid & 63, wid = tid >> 6;
    const int lr = lane & 15, lg = lane >> 4;
    const int wm = wid >> 2, wn = wid & 3;     // 2 x 4 waves
    const int m0 = blockIdx.x * 128;
    const size_t ldB = 2 * (size_t)K;

    f32x4 acc[4][NI];
#pragma unroll
    for (int i = 0; i < 4; ++i)
#pragma unroll
        for (int j = 0; j < NI; ++j)
#pragma unroll
            for (int q = 0; q < 4; ++q) acc[i][j][q] = 0.f;

    const int nK = (3 * K) >> 6;
    for (int kt = 0; kt < nK; ++kt) {
        __syncthreads();
        const int kb = kt * 64;
        const int seg = (kb >= K) ? ((kb >= 2 * K) ? 2 : 1) : 0;
        const int kbA = (seg == 0) ? kb : ((seg == 1) ? kb - K : 512 + (kb - 2 * K));
        const int kbB = (seg == 2) ? kb - 2 * K : kb;
#pragma unroll
        for (int pa = 0; pa < 2; ++pa) {
            int o = tid * 16 + pa * 8192;
            int r = o >> 7;
            int ss = ((o >> 4) & 7) ^ (r & 7);
            gl_lds16(X + (size_t)(m0 + r) * 1024 + kbA + ss * 8,
                     (char*)As + (wid * 1024 + pa * 8192));
        }
#pragma unroll
        for (int pb = 0; pb < NI; ++pb) {
            int o = tid * 16 + pb * 8192;
            int r = o >> 7;
            int ss = ((o >> 4) & 7) ^ (r & 7);
            gl_lds16(W2 + (size_t)r * ldB + kbB + ss * 8,
                     (char*)Bs + (wid * 1024 + pb * 8192));
        }
        __syncthreads();
#pragma unroll
        for (int ks = 0; ks < 2; ++ks) {
            bf16x8 af[4], bf[NI];
#pragma unroll
            for (int mi = 0; mi < 4; ++mi) {
                int row = wm * 64 + mi * 16 + lr;
                af[mi] = *(const bf16x8*)((const char*)As + row * 128 + (((ks * 4 + lg) ^ (row & 7)) * 16));
            }
#pragma unroll
            for (int ni = 0; ni < NI; ++ni) {
                int row = wn * (BN / 4) + ni * 16 + lr;
                bf[ni] = *(const bf16x8*)((const char*)Bs + row * 128 + (((ks * 4 + lg) ^ (row & 7)) * 16));
            }
#pragma unroll
            for (int mi = 0; mi < 4; ++mi)
#pragma unroll
                for (int ni = 0; ni < NI; ++ni)
                    acc[mi][ni] = __builtin_amdgcn_mfma_f32_16x16x32_bf16(af[mi], bf[ni], acc[mi][ni], 0, 0, 0);
        }
    }
#pragma unroll
    for (int ni = 0; ni < NI; ++ni) {
        int gc = wn * (BN / 4) + ni * 16 + lr;
#pragma unroll
        for (int mi = 0; mi < 4; ++mi) {
            int gr0 = m0 + wm * 64 + mi * 16 + lg * 4;
#pragma unroll
            for (int j = 0; j < 4; ++j) {
                float v = acc[mi][ni][j];
                unsigned short hi = f2b(v);
                size_t rb = (size_t)(gr0 + j) * 1024;
                X[rb + gc] = hi;
                X[rb + 512 + gc] = f2b(v - b2f(hi));
            }
        }
    }
}

// ---------- literal per-graph attention on h (from X hi/lo), in place ----------
// h rows read hi+lo -> f32 LDS; literal per-edge CSR softmax (r7-proven);
// messages + bias (+relu) written back hi/lo. LAST: fused literal conn scoring.
template<int LAST, int NDIM>
__global__ __launch_bounds__(256) void attn_lit(
    unsigned short* __restrict__ X,
    const float* __restrict__ avs, const float* __restrict__ avd,
    const float* __restrict__ bias,
    const int* __restrict__ ei, int E,
    const float* __restrict__ wsc, const float* __restrict__ bsp,
    float* __restrict__ outp)
{
    __shared__ float Hs[19 * 520];
    __shared__ float Ho[LAST ? 19 * 260 : 1];
    __shared__ float as_[512], ad_[512], bi_[512];
    __shared__ short srcL[384], dstL[384];
    __shared__ float alphaE[384];
    __shared__ short eidx[384];
    __shared__ int   off[20];
    __shared__ int   cnt[19];
    __shared__ float alS[19], alD[19], mxs[19], sms[19];
    __shared__ float connL[361];
    __shared__ float wl[19];

    const int tid = threadIdx.x;
    const int g = blockIdx.x;
    const size_t base = (size_t)g * 19 * 1024;
    const int Etot = E + 19;
    const int C8 = NDIM >> 3;

    // ---- load h rows (hi+lo), vectors, edges ----
    for (int idx = tid; idx < 19 * C8; idx += 256) {
        int row = idx / C8, c8 = idx % C8;
        uint4 vh = *(const uint4*)(X + base + (size_t)row * 1024 + c8 * 8);
        uint4 vl = *(const uint4*)(X + base + (size_t)row * 1024 + 512 + c8 * 8);
        const unsigned short* ph = (const unsigned short*)&vh;
        const unsigned short* pl = (const unsigned short*)&vl;
#pragma unroll
        for (int j = 0; j < 8; ++j)
            Hs[row * 520 + c8 * 8 + j] = b2f(ph[j]) + b2f(pl[j]);
    }
    for (int c = tid; c < NDIM; c += 256) { as_[c] = avs[c]; ad_[c] = avd[c]; bi_[c] = bias[c]; }
    for (int e = tid; e < E; e += 256) { srcL[e] = (short)ei[e]; dstL[e] = (short)ei[E + e]; }
    if (tid < 19) { srcL[E + tid] = (short)tid; dstL[E + tid] = (short)tid; }
    if (LAST && tid < 19) wl[tid] = wsc[tid];
    if (tid < 19) cnt[tid] = 0;
    __syncthreads();

    // ---- logits al_s = h.a_src, al_d = h.a_dst ----
    if (tid < 19) {
        float a = 0.f;
        const float* hr = &Hs[tid * 520];
        for (int c = 0; c < NDIM; ++c) a += hr[c] * as_[c];
        alS[tid] = a;
    } else if (tid >= 64 && tid < 83) {
        int n = tid - 64;
        float a = 0.f;
        const float* hr = &Hs[n * 520];
        for (int c = 0; c < NDIM; ++c) a += hr[c] * ad_[c];
        alD[n] = a;
    }
    __syncthreads();

    // ---- CSR bucket edges by dst ----
    for (int e = tid; e < Etot; e += 256) atomicAdd(&cnt[dstL[e]], 1);
    __syncthreads();
    if (tid == 0) {
        off[0] = 0;
        for (int n = 0; n < 19; ++n) off[n + 1] = off[n] + cnt[n];
    }
    __syncthreads();
    if (tid < 19) cnt[tid] = 0;
    __syncthreads();
    for (int e = tid; e < Etot; e += 256) {
        int d = dstL[e];
        int p = off[d] + atomicAdd(&cnt[d], 1);
        eidx[p] = (short)e;
    }
    __syncthreads();

    // ---- segment max / sum (literal over edge list) ----
    if (tid < 19) {
        float m = -1e30f;
        float ad = alD[tid];
        for (int j = off[tid]; j < off[tid + 1]; ++j) {
            int e = eidx[j];
            float le = alS[srcL[e]] + ad;
            le = le > 0.f ? le : 0.2f * le;
            m = fmaxf(m, le);
        }
        float s = 0.f;
        for (int j = off[tid]; j < off[tid + 1]; ++j) {
            int e = eidx[j];
            float le = alS[srcL[e]] + ad;
            le = le > 0.f ? le : 0.2f * le;
            s += __expf(le - m);
        }
        mxs[tid] = m; sms[tid] = s;
    }
    __syncthreads();
    for (int e = tid; e < Etot; e += 256) {
        int d = dstL[e];
        float le = alS[srcL[e]] + alD[d];
        le = le > 0.f ? le : 0.2f * le;
        alphaE[e] = __expf(le - mxs[d]) / sms[d];
    }
    __syncthreads();

    // ---- messages + bias (+relu) ----
    for (int idx = tid; idx < 19 * NDIM; idx += 256) {
        int n = idx / NDIM, c = idx % NDIM;
        float acc = 0.f;
        for (int j = off[n]; j < off[n + 1]; ++j) {
            int e = eidx[j];
            acc += alphaE[e] * Hs[srcL[e] * 520 + c];
        }
        float v = acc + bi_[c];
        if (!LAST) {
            v = fmaxf(v, 0.f);
            unsigned short hi = f2b(v);
            X[base + (size_t)n * 1024 + c] = hi;
            X[base + (size_t)n * 1024 + 512 + c] = f2b(v - b2f(hi));
        } else {
            Ho[n * 260 + c] = v;
        }
    }

    if (LAST) {
        __syncthreads();
        // ---- literal scoring: conn = h h^T ; z = conn @ ws + bs ; sigmoid ----
        for (int idx = tid; idx < 361; idx += 256) {
            int n = idx / 19, m = idx % 19;
            float a = 0.f;
            for (int c = 0; c < NDIM; ++c) a += Ho[n * 260 + c] * Ho[m * 260 + c];
            connL[idx] = a;
        }
        __syncthreads();
        if (tid < 19) {
            float z = 0.f;
#pragma unroll
            for (int m = 0; m < 19; ++m) z += connL[tid * 19 + m] * wl[m];
            outp[(size_t)g * 19 + tid] = 1.f / (1.f + __expf(-(z + bsp[0])));
        }
    }
}

// ---------- launch ----------
extern "C" void kernel_launch(void* const* d_in, const int* in_sizes, int n_in,
                              void* d_out, int out_size, void* d_ws, size_t ws_size,
                              hipStream_t stream) {
    const float* x   = (const float*)d_in[0];
    const int*   ei  = (const int*)d_in[1];
    const float* W[4]  = {(const float*)d_in[3], (const float*)d_in[7], (const float*)d_in[11], (const float*)d_in[15]};
    const float* As[4] = {(const float*)d_in[4], (const float*)d_in[8], (const float*)d_in[12], (const float*)d_in[16]};
    const float* Ad[4] = {(const float*)d_in[5], (const float*)d_in[9], (const float*)d_in[13], (const float*)d_in[17]};
    const float* Bi[4] = {(const float*)d_in[6], (const float*)d_in[10], (const float*)d_in[14], (const float*)d_in[18]};
    const float* wsc = (const float*)d_in[19];
    const float* bsp = (const float*)d_in[20];
    float* out = (float*)d_out;

    const int Bq = in_sizes[0] / (19 * 256);   // 4096
    const int M  = Bq * 19;                    // 77824 = 608*128
    const int E  = in_sizes[1] / 2;            // 342
    const int Kd[4] = {256, 512, 512, 512};
    const int Nd[4] = {512, 512, 512, 256};

    // workspace: X [M][1024] shorts (159.4 MB) + W2 (3.1 MB) ~= 162.5 MB
    char* ws = (char*)d_ws;
    unsigned short* X = (unsigned short*)ws;
    char* p = ws + (size_t)M * 1024 * 2;
    unsigned short* W2[4];
    for (int L = 0; L < 4; ++L) { W2[L] = (unsigned short*)p; p += (size_t)2 * Kd[L] * Nd[L] * 2; }

    xcvt_k<<<2048, 256, 0, stream>>>(x, X, (long)M * 64);
    for (int L = 0; L < 4; ++L)
        wtrans_k<<<(Kd[L] * Nd[L] + 255) / 256, 256, 0, stream>>>(W[L], W2[L], Kd[L], Nd[L]);

    // layer 1: h = X W1 ; attn
    gemm_inplace<8><<<M / 128, 512, 0, stream>>>(X, W2[0], Kd[0]);
    attn_lit<0, 512><<<Bq, 256, 0, stream>>>(X, As[0], Ad[0], Bi[0], ei, E, nullptr, nullptr, nullptr);
    // layer 2
    gemm_inplace<8><<<M / 128, 512, 0, stream>>>(X, W2[1], Kd[1]);
    attn_lit<0, 512><<<Bq, 256, 0, stream>>>(X, As[1], Ad[1], Bi[1], ei, E, nullptr, nullptr, nullptr);
    // layer 3
    gemm_inplace<8><<<M / 128, 512, 0, stream>>>(X, W2[2], Kd[2]);
    attn_lit<0, 512><<<Bq, 256, 0, stream>>>(X, As[2], Ad[2], Bi[2], ei, E, nullptr, nullptr, nullptr);
    // layer 4 + scoring
    gemm_inplace<4><<<M / 128, 512, 0, stream>>>(X, W2[3], Kd[3]);
    attn_lit<1, 256><<<Bq, 256, 0, stream>>>(X, As[3], Ad[3], Bi[3], ei, E, wsc, bsp, out);
}

// Round 9
// 1138.077 us; speedup vs baseline: 8.0976x; 2.4430x over previous
//
#include <hip/hip_runtime.h>

typedef short bf16x8 __attribute__((ext_vector_type(8)));
typedef float f32x4 __attribute__((ext_vector_type(4)));

// ---------- helpers ----------
__device__ __forceinline__ unsigned short f2b(float f) {
    unsigned int u = __float_as_uint(f);
    unsigned int r = (u + 0x7FFFu + ((u >> 16) & 1u)) >> 16;   // RNE
    return (unsigned short)r;
}
__device__ __forceinline__ float b2f(unsigned short u) {
    return __uint_as_float(((unsigned int)u) << 16);
}
__device__ __forceinline__ void gl_lds16(const void* g, void* l) {
    __builtin_amdgcn_global_load_lds(
        (const __attribute__((address_space(1))) unsigned int*)g,
        (__attribute__((address_space(3))) unsigned int*)l, 16, 0, 0);
}

// X layout: [M][1024] shorts; hi at cols [0,512), lo at [512,1024); first C valid.

// ---------- prep: x f32 -> X hi/lo (C=256) ----------
__global__ __launch_bounds__(256) void xcvt_k(const float* __restrict__ x,
                                              unsigned short* __restrict__ X, long nq) {
    long i = blockIdx.x * 256L + threadIdx.x;
    long st = gridDim.x * 256L;
    for (; i < nq; i += st) {
        long r = i >> 6; int q = (int)(i & 63);
        float4 v = *(const float4*)(x + r * 256 + q * 4);
        ushort4 h, l;
        h.x = f2b(v.x); l.x = f2b(v.x - b2f(h.x));
        h.y = f2b(v.y); l.y = f2b(v.y - b2f(h.y));
        h.z = f2b(v.z); l.z = f2b(v.z - b2f(h.z));
        h.w = f2b(v.w); l.w = f2b(v.w - b2f(h.w));
        *(ushort4*)(X + r * 1024 + q * 4) = h;
        *(ushort4*)(X + r * 1024 + 512 + q * 4) = l;
    }
}

// ---------- prep: W [K][N] f32 -> W2 [N][2K] = [hi | lo] ----------
__global__ __launch_bounds__(256) void wtrans_k(const float* __restrict__ W,
                                                unsigned short* __restrict__ W2, int K, int N) {
    int idx = blockIdx.x * blockDim.x + threadIdx.x;
    if (idx >= K * N) return;
    int n = idx / K, k = idx % K;
    float w = W[(size_t)k * N + n];
    unsigned short hi = f2b(w);
    size_t b = (size_t)n * 2 * K;
    W2[b + k] = hi;
    W2[b + K + k] = f2b(w - b2f(hi));
}

// ---------- prep: CSR of (edge_index + self loops), graph-independent ----------
// csr layout (ints): off[20] | src_in_csr_order[512] | dst_in_csr_order[512]
__global__ __launch_bounds__(512) void csr_prep(const int* __restrict__ ei, int E,
                                                int* __restrict__ csr) {
    __shared__ int cnt[19], off_s[20];
    __shared__ short sL[512], dL[512];
    int t = threadIdx.x;
    int Etot = E + 19;
    if (t < 19) cnt[t] = 0;
    __syncthreads();
    for (int e = t; e < Etot; e += 512) {
        int s = (e < E) ? ei[e] : (e - E);
        int d = (e < E) ? ei[E + e] : (e - E);
        sL[e] = (short)s; dL[e] = (short)d;
        atomicAdd(&cnt[d], 1);
    }
    __syncthreads();
    if (t == 0) {
        off_s[0] = 0;
        for (int n = 0; n < 19; ++n) off_s[n + 1] = off_s[n] + cnt[n];
    }
    __syncthreads();
    if (t < 19) cnt[t] = 0;
    __syncthreads();
    for (int e = t; e < Etot; e += 512) {
        int d = dL[e];
        int p = off_s[d] + atomicAdd(&cnt[d], 1);
        csr[20 + p] = sL[e];
        csr[20 + 512 + p] = d;
    }
    if (t < 20) csr[t] = off_s[t];
}

// ---------- in-place hi/lo MFMA GEMM + fused logits ----------
// X <- X @ W (no bias/act); alS_g[r] = h[r].avs, alD_g[r] = h[r].avd (exact f32 acc).
template<int NI>   // N = NI*64 (8 -> 512, 4 -> 256)
__global__ __launch_bounds__(512, 2) void gemm_inplace(unsigned short* __restrict__ X,
                                                       const unsigned short* __restrict__ W2,
                                                       int K,
                                                       const float* __restrict__ avs,
                                                       const float* __restrict__ avd,
                                                       float* __restrict__ alS_g,
                                                       float* __restrict__ alD_g) {
    constexpr int BN = NI * 64;
    __shared__ unsigned short As[128 * 64];
    __shared__ unsigned short Bs[BN * 64];
    const int tid = threadIdx.x;
    const int lane = tid & 63, wid = tid >> 6;
    const int lr = lane & 15, lg = lane >> 4;
    const int wm = wid >> 2, wn = wid & 3;     // 2 x 4 waves
    const int m0 = blockIdx.x * 128;
    const size_t ldB = 2 * (size_t)K;

    f32x4 acc[4][NI];
#pragma unroll
    for (int i = 0; i < 4; ++i)
#pragma unroll
        for (int j = 0; j < NI; ++j)
#pragma unroll
            for (int q = 0; q < 4; ++q) acc[i][j][q] = 0.f;

    const int nK = (3 * K) >> 6;
    for (int kt = 0; kt < nK; ++kt) {
        __syncthreads();
        const int kb = kt * 64;
        const int seg = (kb >= K) ? ((kb >= 2 * K) ? 2 : 1) : 0;
        const int kbA = (seg == 0) ? kb : ((seg == 1) ? kb - K : 512 + (kb - 2 * K));
        const int kbB = (seg == 2) ? kb - 2 * K : kb;
#pragma unroll
        for (int pa = 0; pa < 2; ++pa) {
            int o = tid * 16 + pa * 8192;
            int r = o >> 7;
            int ss = ((o >> 4) & 7) ^ (r & 7);
            gl_lds16(X + (size_t)(m0 + r) * 1024 + kbA + ss * 8,
                     (char*)As + (wid * 1024 + pa * 8192));
        }
#pragma unroll
        for (int pb = 0; pb < NI; ++pb) {
            int o = tid * 16 + pb * 8192;
            int r = o >> 7;
            int ss = ((o >> 4) & 7) ^ (r & 7);
            gl_lds16(W2 + (size_t)r * ldB + kbB + ss * 8,
                     (char*)Bs + (wid * 1024 + pb * 8192));
        }
        __syncthreads();
#pragma unroll
        for (int ks = 0; ks < 2; ++ks) {
            bf16x8 af[4], bf[NI];
#pragma unroll
            for (int mi = 0; mi < 4; ++mi) {
                int row = wm * 64 + mi * 16 + lr;
                af[mi] = *(const bf16x8*)((const char*)As + row * 128 + (((ks * 4 + lg) ^ (row & 7)) * 16));
            }
#pragma unroll
            for (int ni = 0; ni < NI; ++ni) {
                int row = wn * (BN / 4) + ni * 16 + lr;
                bf[ni] = *(const bf16x8*)((const char*)Bs + row * 128 + (((ks * 4 + lg) ^ (row & 7)) * 16));
            }
#pragma unroll
            for (int mi = 0; mi < 4; ++mi)
#pragma unroll
                for (int ni = 0; ni < NI; ++ni)
                    acc[mi][ni] = __builtin_amdgcn_mfma_f32_16x16x32_bf16(af[mi], bf[ni], acc[mi][ni], 0, 0, 0);
        }
    }
    // ---- X hi/lo stores ----
#pragma unroll
    for (int ni = 0; ni < NI; ++ni) {
        int gc = wn * (BN / 4) + ni * 16 + lr;
#pragma unroll
        for (int mi = 0; mi < 4; ++mi) {
            int gr0 = m0 + wm * 64 + mi * 16 + lg * 4;
#pragma unroll
            for (int j = 0; j < 4; ++j) {
                float v = acc[mi][ni][j];
                unsigned short hi = f2b(v);
                size_t rb = (size_t)(gr0 + j) * 1024;
                X[rb + gc] = hi;
                X[rb + 512 + gc] = f2b(v - b2f(hi));
            }
        }
    }
    // ---- fused logits: per-row h.avs / h.avd (re-use As LDS after barrier) ----
    __syncthreads();
    float* partS = (float*)As;           // [4][128]
    float* partD = partS + 512;          // [4][128]
    float avsv[NI], avdv[NI];
#pragma unroll
    for (int ni = 0; ni < NI; ++ni) {
        int gc = wn * (BN / 4) + ni * 16 + lr;
        avsv[ni] = avs[gc]; avdv[ni] = avd[gc];
    }
#pragma unroll
    for (int mi = 0; mi < 4; ++mi)
#pragma unroll
        for (int j = 0; j < 4; ++j) {
            float s = 0.f, d = 0.f;
#pragma unroll
            for (int ni = 0; ni < NI; ++ni) {
                float v = acc[mi][ni][j];
                s += v * avsv[ni]; d += v * avdv[ni];
            }
            s += __shfl_xor(s, 1); s += __shfl_xor(s, 2);
            s += __shfl_xor(s, 4); s += __shfl_xor(s, 8);
            d += __shfl_xor(d, 1); d += __shfl_xor(d, 2);
            d += __shfl_xor(d, 4); d += __shfl_xor(d, 8);
            if (lr == 0) {
                int row = wm * 64 + mi * 16 + lg * 4 + j;
                partS[wn * 128 + row] = s;
                partD[wn * 128 + row] = d;
            }
        }
    __syncthreads();
    if (tid < 128) {
        float s = partS[tid] + partS[128 + tid] + partS[256 + tid] + partS[384 + tid];
        float d = partD[tid] + partD[128 + tid] + partD[256 + tid] + partD[384 + tid];
        alS_g[m0 + tid] = s;
        alD_g[m0 + tid] = d;
    }
}

// ---------- attention v2: literal CSR softmax -> dense A2 -> register mix ----------
template<int LAST, int NDIM, int CPT>    // CPT = NDIM/256 cols per thread
__global__ __launch_bounds__(256) void attn_v2(
    unsigned short* __restrict__ X,
    const float* __restrict__ bias,
    const int* __restrict__ csr, int E,
    const float* __restrict__ alS_g, const float* __restrict__ alD_g,
    const float* __restrict__ wsc, const float* __restrict__ bsp,
    float* __restrict__ outp)
{
    __shared__ __attribute__((aligned(16))) float A2s[400];   // [19][20] padded
    __shared__ float alSs[19], alDs[19], mxs[19], sms[19];
    __shared__ short csrc[512], cdst[512];
    __shared__ int   offs[20];
    __shared__ float Ho[LAST ? 19 * 264 : 1];
    __shared__ float connL[LAST ? 361 : 1];
    __shared__ float wl[LAST ? 19 : 1];

    const int tid = threadIdx.x;
    const int g = blockIdx.x;
    const size_t base = (size_t)g * 19 * 1024;
    const int Etot = E + 19;

    // ---- P0: load CSR, logits; zero A2 ----
    for (int i = tid; i < Etot; i += 256) {
        csrc[i] = (short)csr[20 + i];
        cdst[i] = (short)csr[20 + 512 + i];
    }
    if (tid < 20) offs[tid] = csr[tid];
    if (tid < 19) alSs[tid] = alS_g[g * 19 + tid];
    else if (tid >= 32 && tid < 51) alDs[tid - 32] = alD_g[g * 19 + tid - 32];
    for (int i = tid; i < 400; i += 256) A2s[i] = 0.f;
    if (LAST && tid < 19) wl[tid] = wsc[tid];
    __syncthreads();

    // ---- P1: literal segment max/sum walks (r7/r8-proven FP order) ----
    if (tid < 19) {
        float ad = alDs[tid];
        float m = -1e30f;
        for (int j = offs[tid]; j < offs[tid + 1]; ++j) {
            float le = alSs[csrc[j]] + ad;
            le = le > 0.f ? le : 0.2f * le;
            m = fmaxf(m, le);
        }
        float ssum = 0.f;
        for (int j = offs[tid]; j < offs[tid + 1]; ++j) {
            float le = alSs[csrc[j]] + ad;
            le = le > 0.f ? le : 0.2f * le;
            ssum += __expf(le - m);
        }
        mxs[tid] = m; sms[tid] = ssum;
    }
    __syncthreads();

    // ---- P2: alpha -> dense A2 (duplicate edges accumulate) ----
    for (int j = tid; j < Etot; j += 256) {
        int d = cdst[j], s = csrc[j];
        float le = alSs[s] + alDs[d];
        le = le > 0.f ? le : 0.2f * le;
        atomicAdd(&A2s[d * 20 + s], __expf(le - mxs[d]) / sms[d]);
    }
    __syncthreads();

    // ---- P3: column-local register mix ----
    const int c0 = tid * CPT;
    float hv[19][CPT];
#pragma unroll
    for (int m = 0; m < 19; ++m) {
        if (CPT == 2) {
            unsigned int uh = *(const unsigned int*)(X + base + (size_t)m * 1024 + c0);
            unsigned int ul = *(const unsigned int*)(X + base + (size_t)m * 1024 + 512 + c0);
            hv[m][0] = b2f((unsigned short)uh) + b2f((unsigned short)ul);
            hv[m][CPT - 1] = b2f((unsigned short)(uh >> 16)) + b2f((unsigned short)(ul >> 16));
        } else {
            hv[m][0] = b2f(X[base + (size_t)m * 1024 + c0]) +
                       b2f(X[base + (size_t)m * 1024 + 512 + c0]);
        }
    }
    float accv[19][CPT];
#pragma unroll
    for (int n = 0; n < 19; ++n)
#pragma unroll
        for (int cc = 0; cc < CPT; ++cc) accv[n][cc] = 0.f;
#pragma unroll
    for (int n = 0; n < 19; ++n) {
#pragma unroll
        for (int mq = 0; mq < 5; ++mq) {
            f32x4 a = *(const f32x4*)&A2s[n * 20 + mq * 4];
#pragma unroll
            for (int t = 0; t < 4; ++t) {
                int m = mq * 4 + t;
                if (m < 19) {
#pragma unroll
                    for (int cc = 0; cc < CPT; ++cc) accv[n][cc] += a[t] * hv[m][cc];
                }
            }
        }
    }

    if (!LAST) {
        float bv[CPT];
#pragma unroll
        for (int cc = 0; cc < CPT; ++cc) bv[cc] = bias[c0 + cc];
#pragma unroll
        for (int n = 0; n < 19; ++n) {
            unsigned int ph = 0, pl = 0;
#pragma unroll
            for (int cc = 0; cc < CPT; ++cc) {
                float v = fmaxf(accv[n][cc] + bv[cc], 0.f);
                unsigned short hi = f2b(v);
                unsigned short lo = f2b(v - b2f(hi));
                ph |= ((unsigned int)hi) << (16 * cc);
                pl |= ((unsigned int)lo) << (16 * cc);
            }
            if (CPT == 2) {
                *(unsigned int*)(X + base + (size_t)n * 1024 + c0) = ph;
                *(unsigned int*)(X + base + (size_t)n * 1024 + 512 + c0) = pl;
            } else {
                X[base + (size_t)n * 1024 + c0] = (unsigned short)ph;
                X[base + (size_t)n * 1024 + 512 + c0] = (unsigned short)pl;
            }
        }
    } else {
        // out rows (with bias, no relu) to LDS, then literal conn scoring
#pragma unroll
        for (int n = 0; n < 19; ++n)
            Ho[n * 264 + c0] = accv[n][0] + bias[c0];
        __syncthreads();
        for (int idx = tid; idx < 361; idx += 256) {
            int n = idx / 19, m = idx % 19;
            float a = 0.f;
            for (int c = 0; c < 256; ++c) a += Ho[n * 264 + c] * Ho[m * 264 + c];
            connL[idx] = a;
        }
        __syncthreads();
        if (tid < 19) {
            float z = 0.f;
#pragma unroll
            for (int m = 0; m < 19; ++m) z += connL[tid * 19 + m] * wl[m];
            outp[(size_t)g * 19 + tid] = 1.f / (1.f + __expf(-(z + bsp[0])));
        }
    }
}

// ---------- launch ----------
extern "C" void kernel_launch(void* const* d_in, const int* in_sizes, int n_in,
                              void* d_out, int out_size, void* d_ws, size_t ws_size,
                              hipStream_t stream) {
    const float* x   = (const float*)d_in[0];
    const int*   ei  = (const int*)d_in[1];
    const float* W[4]  = {(const float*)d_in[3], (const float*)d_in[7], (const float*)d_in[11], (const float*)d_in[15]};
    const float* As[4] = {(const float*)d_in[4], (const float*)d_in[8], (const float*)d_in[12], (const float*)d_in[16]};
    const float* Ad[4] = {(const float*)d_in[5], (const float*)d_in[9], (const float*)d_in[13], (const float*)d_in[17]};
    const float* Bi[4] = {(const float*)d_in[6], (const float*)d_in[10], (const float*)d_in[14], (const float*)d_in[18]};
    const float* wsc = (const float*)d_in[19];
    const float* bsp = (const float*)d_in[20];
    float* out = (float*)d_out;

    const int Bq = in_sizes[0] / (19 * 256);   // 4096
    const int M  = Bq * 19;                    // 77824 = 608*128
    const int E  = in_sizes[1] / 2;            // 342
    const int Kd[4] = {256, 512, 512, 512};
    const int Nd[4] = {512, 512, 512, 256};

    // ws: X (159.4MB) | W2 x4 (3.15MB) | alS (311KB) | alD (311KB) | csr (4.2KB)
    char* ws = (char*)d_ws;
    unsigned short* X = (unsigned short*)ws;
    char* p = ws + (size_t)M * 1024 * 2;
    unsigned short* W2[4];
    for (int L = 0; L < 4; ++L) { W2[L] = (unsigned short*)p; p += (size_t)2 * Kd[L] * Nd[L] * 2; }
    float* alSg = (float*)p; p += (size_t)M * 4;
    float* alDg = (float*)p; p += (size_t)M * 4;
    int* csr = (int*)p;

    xcvt_k<<<2048, 256, 0, stream>>>(x, X, (long)M * 64);
    csr_prep<<<1, 512, 0, stream>>>(ei, E, csr);
    for (int L = 0; L < 4; ++L)
        wtrans_k<<<(Kd[L] * Nd[L] + 255) / 256, 256, 0, stream>>>(W[L], W2[L], Kd[L], Nd[L]);

    gemm_inplace<8><<<M / 128, 512, 0, stream>>>(X, W2[0], Kd[0], As[0], Ad[0], alSg, alDg);
    attn_v2<0, 512, 2><<<Bq, 256, 0, stream>>>(X, Bi[0], csr, E, alSg, alDg, nullptr, nullptr, nullptr);
    gemm_inplace<8><<<M / 128, 512, 0, stream>>>(X, W2[1], Kd[1], As[1], Ad[1], alSg, alDg);
    attn_v2<0, 512, 2><<<Bq, 256, 0, stream>>>(X, Bi[1], csr, E, alSg, alDg, nullptr, nullptr, nullptr);
    gemm_inplace<8><<<M / 128, 512, 0, stream>>>(X, W2[2], Kd[2], As[2], Ad[2], alSg, alDg);
    attn_v2<0, 512, 2><<<Bq, 256, 0, stream>>>(X, Bi[2], csr, E, alSg, alDg, nullptr, nullptr, nullptr);
    gemm_inplace<4><<<M / 128, 512, 0, stream>>>(X, W2[3], Kd[3], As[3], Ad[3], alSg, alDg);
    attn_v2<1, 256, 1><<<Bq, 256, 0, stream>>>(X, Bi[3], csr, E, alSg, alDg, wsc, bsp, out);
}